// Round 1
// baseline (175.410 us; speedup 1.0000x reference)
//
#include <hip/hip_runtime.h>

typedef __bf16 bf16_t;
typedef bf16_t bf16x8 __attribute__((ext_vector_type(8)));
typedef float f32x4 __attribute__((ext_vector_type(4)));

#define NB 8
#define TT 2048
#define DIN 1024
#define HH 64
#define MM (NB * TT)

__device__ __forceinline__ unsigned short f2bf(float f) {
    unsigned int u = __float_as_uint(f);
    u += 0x7fffu + ((u >> 16) & 1u);   // round-to-nearest-even
    return (unsigned short)(u >> 16);
}

// async global->LDS, 16B per lane. LDS dest = base + lane*16 (linear);
// global src may be per-lane (16B-aligned). Exec-masked.
__device__ __forceinline__ void async16(void* l, const void* g) {
    __builtin_amdgcn_global_load_lds(
        (const __attribute__((address_space(1))) unsigned int*)g,
        (__attribute__((address_space(3))) unsigned int*)l, 16, 0, 0);
}

// Per-block dtype probe: low-bf16 exponent field of x words.
// fp32 data -> ~20% in range; bf16 -> ~100%. Returns 1 if fp32.
__device__ __forceinline__ int block_detect_f32(const unsigned int* __restrict__ xw,
                                                int tid, int* sflag) {
    if (tid < 64) {
        unsigned int u = xw[tid];
        unsigned int e = (u >> 7) & 0xFFu;
        unsigned long long m = __ballot(e >= 100u && e <= 150u);
        if (tid == 0) *sflag = (__popcll(m) < 48) ? 1 : 0;
    }
    __syncthreads();
    return *sflag;
}

// ------------------------------------------------------------------
// LDS-tiled W transpose: Wt[w*64+n][k] = W_w[k][n], bf16.
// ------------------------------------------------------------------
__global__ __launch_bounds__(256) void transpose_w_kernel(
    const void* __restrict__ Wq, const void* __restrict__ Wk,
    const void* __restrict__ Wv, const unsigned int* __restrict__ xw,
    unsigned short* __restrict__ Wt) {
    __shared__ int sflag;
    __shared__ unsigned short ts[64][68];
    const int tid = threadIdx.x;
    const int isf32 = block_detect_f32(xw, tid, &sflag);
    const int w = blockIdx.x >> 4, kt = blockIdx.x & 15;
    const void* W = (w == 0) ? Wq : (w == 1) ? Wk : Wv;
    const int kk = tid >> 4, nn = (tid & 15) * 4;
#pragma unroll
    for (int j = 0; j < 4; ++j) {
        int k = kk + j * 16;
        if (isf32) {
            float4 f = *(const float4*)((const float*)W + (size_t)(kt * 64 + k) * 64 + nn);
            ts[k][nn + 0] = f2bf(f.x); ts[k][nn + 1] = f2bf(f.y);
            ts[k][nn + 2] = f2bf(f.z); ts[k][nn + 3] = f2bf(f.w);
        } else {
            *(uint2*)&ts[k][nn] =
                *(const uint2*)((const unsigned short*)W + (size_t)(kt * 64 + k) * 64 + nn);
        }
    }
    __syncthreads();
    const int n = tid >> 2, k0 = (tid & 3) * 16;
    unsigned short tmp[16];
#pragma unroll
    for (int j = 0; j < 16; ++j) tmp[j] = ts[k0 + j][n];
    unsigned short* dst = Wt + (size_t)(w * 64 + n) * 1024 + kt * 64 + k0;
    *(uint4*)(dst + 0) = *(uint4*)&tmp[0];
    *(uint4*)(dst + 8) = *(uint4*)&tmp[8];
}

// ------------------------------------------------------------------
// Fused QKV projection v7: double-buffered LDS (xs, wlds), stage tile
// t+1 BEFORE computing tile t -> ONE barrier per K-iter (17 vs 32) and
// the async16 drain is covered by ~480cy of MFMA (2-phase recipe).
// XCD-pair swizzle: swz=(bid&7)*64+(bid>>3); nh-pair (same x stripe)
// lands on the SAME XCD (x read #2 = L2 hit) and XCD x computes
// exactly batch x's q/k/vt (L2-resident for attn, which pins b=XCD).
// ------------------------------------------------------------------
#define XR 72      /* x LDS row stride in bf16 elems (144 B) */
#define WROWC 9    /* W LDS row = 9 chunks = 144 B (128 payload) */

__global__ __launch_bounds__(256, 2) void proj_kernel(
    const void* __restrict__ xraw, const unsigned short* __restrict__ Wt,
    unsigned short* __restrict__ qbuf, unsigned short* __restrict__ kbuf,
    unsigned short* __restrict__ vtbuf) {
    __shared__ int sflag;
    __shared__ __align__(16) unsigned short xs[2][64 * XR];            // 18432 B
    __shared__ __align__(16) unsigned char wlds[2][96 * WROWC * 16];   // 27648 B

    const int tid = threadIdx.x;
    const int isf32 = block_detect_f32((const unsigned int*)xraw, tid, &sflag);
    const int bid = blockIdx.x;                 // 0..511
    const int swz = (bid & 7) * 64 + (bid >> 3);  // bijective (512%8==0)
    const int nh = swz & 1;                     // N cols nh*96 .. nh*96+95
    const int m0 = (swz >> 1) * 64;
    const int wave = tid >> 6, lane = tid & 63, quad = lane >> 4, l15 = lane & 15;
    const int rw = wave & 1, cw = wave >> 1;    // rows rw*32.., cols cw*48..

    const float* xf = (const float*)xraw;
    const unsigned short* xb = (const unsigned short*)xraw;
    const unsigned char* wg = (const unsigned char*)Wt;

    // W staging: 96 rows * 9 chunks = 864 chunks, guarded
    const unsigned char* wsrc[4];
    unsigned int wdst[4];
    int nw = 0;
#pragma unroll
    for (int j = 0; j < 4; ++j) {
        int c = (wave + 4 * j) * 64 + lane;
        if (c < 864) {
            int R = c / WROWC, cc = c % WROWC;
            int ccu = (cc > 7) ? 0 : cc;
            wsrc[nw] = wg + (size_t)(nh * 96 + R) * 2048 + ccu * 16;
            wdst[nw] = c * 16;
            ++nw;
        }
    }

    // x reg staging role: thread -> row xr (0..63), 16 cols at xc
    const int xr = tid >> 2, xc = (tid & 3) * 16;
    float4 px[4];
    uint4  pxb[2];
    auto ldx = [&](int k0) {
        if (isf32) {
            const float* g = xf + (size_t)(m0 + xr) * DIN + k0 + xc;
#pragma unroll
            for (int j = 0; j < 4; ++j) px[j] = *(const float4*)(g + j * 4);
        } else {
            const unsigned short* g = xb + (size_t)(m0 + xr) * DIN + k0 + xc;
            pxb[0] = *(const uint4*)(g + 0);
            pxb[1] = *(const uint4*)(g + 8);
        }
    };
    auto writeX = [&](int buf) {
        if (isf32) {
            unsigned short t[16];
#pragma unroll
            for (int j = 0; j < 4; ++j) {
                t[j * 4 + 0] = f2bf(px[j].x); t[j * 4 + 1] = f2bf(px[j].y);
                t[j * 4 + 2] = f2bf(px[j].z); t[j * 4 + 3] = f2bf(px[j].w);
            }
            *(uint4*)&xs[buf][xr * XR + xc + 0] = *(uint4*)&t[0];
            *(uint4*)&xs[buf][xr * XR + xc + 8] = *(uint4*)&t[8];
        } else {
            *(uint4*)&xs[buf][xr * XR + xc + 0] = pxb[0];
            *(uint4*)&xs[buf][xr * XR + xc + 8] = pxb[1];
        }
    };
    auto stageW = [&](int buf, int itk) {
        const size_t off = (size_t)itk * 128;
        for (int j = 0; j < nw; ++j) async16(&wlds[buf][wdst[j]], wsrc[j] + off);
    };

    f32x4 acc[2][3];
#pragma unroll
    for (int rt = 0; rt < 2; ++rt)
#pragma unroll
        for (int ct = 0; ct < 3; ++ct)
            acc[rt][ct] = (f32x4){0.f, 0.f, 0.f, 0.f};

    auto compute = [&](int buf) {
#pragma unroll
        for (int ks = 0; ks < 2; ++ks) {
            bf16x8 a[2], b[3];
#pragma unroll
            for (int rt = 0; rt < 2; ++rt)
                a[rt] = *(const bf16x8*)
                    &xs[buf][(rw * 32 + rt * 16 + l15) * XR + ks * 32 + quad * 8];
#pragma unroll
            for (int ct = 0; ct < 3; ++ct)
                b[ct] = *(const bf16x8*)
                    &wlds[buf][(cw * 48 + ct * 16 + l15) * (WROWC * 16) + ks * 64 + quad * 16];
#pragma unroll
            for (int rt = 0; rt < 2; ++rt)
#pragma unroll
                for (int ct = 0; ct < 3; ++ct)
                    acc[rt][ct] = __builtin_amdgcn_mfma_f32_16x16x32_bf16(
                        a[rt], b[ct], acc[rt][ct], 0, 0, 0);
        }
    };

    // prologue: stage tile 0, start x load for tile 1
    ldx(0);
    writeX(0);
    stageW(0, 0);
    ldx(64);
    __syncthreads();   // drains stage(0); visible to all

    for (int it = 0; it < 16; ++it) {
        if (it < 15) {
            writeX((it + 1) & 1);          // consumes px (tile it+1)
            stageW((it + 1) & 1, it + 1);  // async16, drained by end-barrier
            if (it < 14) ldx((it + 2) * 64);
        }
        compute(it & 1);
        __syncthreads();   // compute(it) done + staging(it+1) complete/visible
    }

    // epilogue: D[row=quad*4+reg][col=l15]
#pragma unroll
    for (int rt = 0; rt < 2; ++rt)
#pragma unroll
        for (int ct = 0; ct < 3; ++ct) {
            int n = nh * 96 + cw * 48 + ct * 16 + l15;
            int wsel = n >> 6, nn = n & 63;
#pragma unroll
            for (int reg = 0; reg < 4; ++reg) {
                int m = m0 + rw * 32 + rt * 16 + quad * 4 + reg;
                unsigned short bv = f2bf(acc[rt][ct][reg]);
                if (wsel == 0)      qbuf[(size_t)m * HH + nn] = bv;
                else if (wsel == 1) kbuf[(size_t)m * HH + nn] = bv;
                else {
                    int bb = m >> 11, t = m & 2047;
                    vtbuf[((size_t)bb * HH + nn) * TT + t] = bv;
                }
            }
        }
}

// ------------------------------------------------------------------
// Split-column flash attention, FIXED exponent shift (no online max;
// partials are directly summable). Linear grid 640: b = bid&7 pins
// batch b to XCD b (its 0.75 MB K/Q/VT slice is L2-resident there,
// written by proj on the same XCD). T14 async-STAGE split: next K/V
// tile's global loads issued right after QK^T, latency hidden under
// softmax+PV; LDS write happens at top of next iter after barrier.
// ------------------------------------------------------------------
__global__ __launch_bounds__(256, 4) void attn_kernel(
    const unsigned short* __restrict__ rowbuf,  // k-proj [b][t][h]
    const unsigned short* __restrict__ colbuf,  // q-proj [b][s][h]
    const unsigned short* __restrict__ vtbuf,   // [b][h][s]
    float* __restrict__ O_part,                 // [slot][64][64]
    float* __restrict__ l_part) {               // [slot][64]

    __shared__ __align__(16) unsigned short Qr_s[64][72];
    __shared__ __align__(16) unsigned short Kc_s[64][72];
    __shared__ __align__(16) unsigned short Vt_s[64][72];
    __shared__ __align__(16) unsigned short P_s[4][16][72];

    const int tid  = threadIdx.x;
    const int bid  = blockIdx.x;   // 0..639
    const int b    = bid & 7;      // XCD-pinned batch
    const int bx   = bid >> 3;     // 0..79
    int rt, ch;
    if (bx < 8)       { rt = bx;                 ch = 0; }
    else if (bx < 24) { rt = 8 + ((bx - 8) >> 1);  ch = (bx - 8) & 1; }
    else if (bx < 48) { rt = 16 + (bx - 24) / 3;   ch = (bx - 24) % 3; }
    else              { rt = 24 + ((bx - 48) >> 2); ch = (bx - 48) & 3; }
    const int nct = min(8, rt + 1 - ch * 8);
    const int t0 = rt * 64;
    const int slot = b * 80 + bx;

    const int wave = tid >> 6, lane = tid & 63, quad = lane >> 4, l15 = lane & 15;
    const int sr = tid >> 2, sc = (tid & 3) * 16;

    {
        const uint4* g = (const uint4*)(rowbuf + ((size_t)b * TT + t0 + sr) * HH + sc);
        *(uint4*)&Qr_s[sr][sc + 0] = g[0];
        *(uint4*)&Qr_s[sr][sc + 8] = g[1];
    }

    f32x4 o[4];
#pragma unroll
    for (int c = 0; c < 4; ++c) o[c] = (f32x4){0.f, 0.f, 0.f, 0.f};
    float ls[4] = {0.f, 0.f, 0.f, 0.f};

    const float SCL2 = 0.125f * 1.4426950408889634f;  // H^-0.5 * log2(e)

    // register prefetch of K/V tile (16 VGPRs, consumed at loop top)
    uint4 pk0, pk1, pv0, pv1;
    auto loadKV = [&](int i) {
        const int s0 = (ch * 8 + i) * 64;
        const uint4* gk = (const uint4*)(colbuf + ((size_t)b * TT + s0 + sr) * HH + sc);
        pk0 = gk[0]; pk1 = gk[1];
        const uint4* gv = (const uint4*)(vtbuf + ((size_t)b * HH + sr) * TT + s0 + sc);
        pv0 = gv[0]; pv1 = gv[1];
    };
    loadKV(0);

    for (int i = 0; i < nct; ++i) {
        const int stc = ch * 8 + i;
        const int s0 = stc * 64;
        *(uint4*)&Kc_s[sr][sc + 0] = pk0;
        *(uint4*)&Kc_s[sr][sc + 8] = pk1;
        *(uint4*)&Vt_s[sr][sc + 0] = pv0;
        *(uint4*)&Vt_s[sr][sc + 8] = pv1;
        __syncthreads();

        f32x4 scf[4];
#pragma unroll
        for (int c = 0; c < 4; ++c) scf[c] = (f32x4){0.f, 0.f, 0.f, 0.f};
#pragma unroll
        for (int ks = 0; ks < 2; ++ks) {
            bf16x8 a = *(const bf16x8*)&Qr_s[wave * 16 + l15][ks * 32 + quad * 8];
#pragma unroll
            for (int c = 0; c < 4; ++c) {
                bf16x8 bb = *(const bf16x8*)&Kc_s[c * 16 + l15][ks * 32 + quad * 8];
                scf[c] = __builtin_amdgcn_mfma_f32_16x16x32_bf16(a, bb, scf[c], 0, 0, 0);
            }
        }

        // issue next tile's global loads NOW; latency hides under softmax+PV
        if (i + 1 < nct) loadKV(i + 1);

        const bool diag = (stc == rt);
#pragma unroll
        for (int r = 0; r < 4; ++r) {
            const int tg = t0 + wave * 16 + quad * 4 + r;
#pragma unroll
            for (int c = 0; c < 4; ++c) {
                float arg = fmaf(scf[c][r], SCL2, -30.f);
                if (diag && (s0 + c * 16 + l15) > tg) arg = -200.f;
                float p = __builtin_amdgcn_exp2f(arg);
                P_s[wave][quad * 4 + r][c * 16 + l15] = f2bf(p);
                ls[r] += p;
            }
        }
        // P_s is per-wave: intra-wave LDS RAW, compiler lgkmcnt suffices.
#pragma unroll
        for (int ks = 0; ks < 2; ++ks) {
            bf16x8 ap = *(const bf16x8*)&P_s[wave][l15][ks * 32 + quad * 8];
#pragma unroll
            for (int c = 0; c < 4; ++c) {
                bf16x8 bv = *(const bf16x8*)&Vt_s[c * 16 + l15][ks * 32 + quad * 8];
                o[c] = __builtin_amdgcn_mfma_f32_16x16x32_bf16(ap, bv, o[c], 0, 0, 0);
            }
        }
        __syncthreads();   // Kc/Vt consumed; safe to restage
    }

    // per-row l: reduce over the 16 l15 lanes (once, at the end)
#pragma unroll
    for (int r = 0; r < 4; ++r) {
#pragma unroll
        for (int off = 1; off < 16; off <<= 1) ls[r] += __shfl_xor(ls[r], off);
    }
    if (l15 == 0) {
#pragma unroll
        for (int r = 0; r < 4; ++r)
            l_part[(size_t)slot * 64 + wave * 16 + quad * 4 + r] = ls[r];
    }
#pragma unroll
    for (int c = 0; c < 4; ++c)
#pragma unroll
        for (int r = 0; r < 4; ++r)
            O_part[(size_t)slot * 4096 + (wave * 16 + quad * 4 + r) * 64 + c * 16 + l15] = o[c][r];
}

// ------------------------------------------------------------------
// Combine partials: out = (sum O_part) / (sum l_part). Linear grid
// 256, b = bid&7 -> same-XCD L2 reuse of O_part written by attn.
// ------------------------------------------------------------------
__global__ __launch_bounds__(256) void combine_kernel(
    const float* __restrict__ O_part, const float* __restrict__ l_part,
    const unsigned int* __restrict__ xw, void* __restrict__ outraw) {
    __shared__ int sflag;
    const int tid = threadIdx.x;
    const int isf32 = block_detect_f32(xw, tid, &sflag);
    const int bid = blockIdx.x;
    const int b = bid & 7, rt = bid >> 3;
    const int nch = rt / 8 + 1;
    const int off = (rt < 8) ? rt : (rt < 16) ? 8 + 2 * (rt - 8)
                   : (rt < 24) ? 24 + 3 * (rt - 16) : 48 + 4 * (rt - 24);
    const int slot0 = b * 80 + off;

    const int row = tid >> 2, cb = (tid & 3) * 16;
    f32x4 a[4];
#pragma unroll
    for (int q = 0; q < 4; ++q) a[q] = (f32x4){0.f, 0.f, 0.f, 0.f};
    float l = 0.f;
    for (int j = 0; j < nch; ++j) {
        const f32x4* p = (const f32x4*)(O_part + (size_t)(slot0 + j) * 4096 + row * 64 + cb);
#pragma unroll
        for (int q = 0; q < 4; ++q) a[q] += p[q];
        l += l_part[(size_t)(slot0 + j) * 64 + row];
    }
    const float inv = 1.f / l;
    const size_t base = ((size_t)b * TT + rt * 64 + row) * HH + cb;
    if (isf32) {
        float* outf = (float*)outraw;
#pragma unroll
        for (int q = 0; q < 4; ++q) {
            f32x4 v = a[q] * inv;
            *(f32x4*)(outf + base + q * 4) = v;
        }
    } else {
        unsigned short h[16];
#pragma unroll
        for (int q = 0; q < 4; ++q)
#pragma unroll
            for (int e = 0; e < 4; ++e) h[q * 4 + e] = f2bf(a[q][e] * inv);
        unsigned short* outb = (unsigned short*)outraw;
        *(uint4*)(outb + base + 0) = *(uint4*)&h[0];
        *(uint4*)(outb + base + 8) = *(uint4*)&h[8];
    }
}

extern "C" void kernel_launch(void* const* d_in, const int* in_sizes, int n_in,
                              void* d_out, int out_size, void* d_ws, size_t ws_size,
                              hipStream_t stream) {
    const void* x  = d_in[0];
    const void* Wq = d_in[1];
    const void* Wk = d_in[2];
    const void* Wv = d_in[3];
    unsigned short* ws = (unsigned short*)d_ws;

    unsigned short* qbuf  = ws;                          // 2 MB
    unsigned short* kbuf  = ws + (size_t)MM * HH;        // 2 MB
    unsigned short* vtbuf = ws + (size_t)2 * MM * HH;    // 2 MB
    unsigned short* wtbuf = ws + (size_t)3 * MM * HH;    // 384 KB
    float* O_part = (float*)(ws + (size_t)3 * MM * HH + 3 * 65536);  // 10.5 MB
    float* l_part = O_part + (size_t)640 * 4096;                      // 164 KB

    hipLaunchKernelGGL(transpose_w_kernel, dim3(48), dim3(256), 0, stream,
                       Wq, Wk, Wv, (const unsigned int*)x, wtbuf);
    hipLaunchKernelGGL(proj_kernel, dim3(512), dim3(256), 0, stream,
                       x, wtbuf, qbuf, kbuf, vtbuf);
    hipLaunchKernelGGL(attn_kernel, dim3(640), dim3(256), 0, stream,
                       kbuf, qbuf, vtbuf, O_part, l_part);
    hipLaunchKernelGGL(combine_kernel, dim3(256), dim3(256), 0, stream,
                       O_part, l_part, (const unsigned int*)x, d_out);
}

// Round 2
// 154.517 us; speedup vs baseline: 1.1352x; 1.1352x over previous
//
#include <hip/hip_runtime.h>

typedef __bf16 bf16_t;
typedef bf16_t bf16x8 __attribute__((ext_vector_type(8)));
typedef float f32x4 __attribute__((ext_vector_type(4)));

#define NB 8
#define TT 2048
#define DIN 1024
#define HH 64
#define MM (NB * TT)

__device__ __forceinline__ unsigned short f2bf(float f) {
    unsigned int u = __float_as_uint(f);
    u += 0x7fffu + ((u >> 16) & 1u);   // round-to-nearest-even
    return (unsigned short)(u >> 16);
}

// async global->LDS, 16B per lane. LDS dest = base + lane*16 (linear);
// global src may be per-lane (16B-aligned). Exec-masked.
__device__ __forceinline__ void async16(void* l, const void* g) {
    __builtin_amdgcn_global_load_lds(
        (const __attribute__((address_space(1))) unsigned int*)g,
        (__attribute__((address_space(3))) unsigned int*)l, 16, 0, 0);
}

// Per-block dtype probe: low-bf16 exponent field of x words.
// fp32 data -> ~20% in range; bf16 -> ~100%. Returns 1 if fp32.
__device__ __forceinline__ int block_detect_f32(const unsigned int* __restrict__ xw,
                                                int tid, int* sflag) {
    if (tid < 64) {
        unsigned int u = xw[tid];
        unsigned int e = (u >> 7) & 0xFFu;
        unsigned long long m = __ballot(e >= 100u && e <= 150u);
        if (tid == 0) *sflag = (__popcll(m) < 48) ? 1 : 0;
    }
    __syncthreads();
    return *sflag;
}

// ------------------------------------------------------------------
// LDS-tiled W transpose: Wt[w*64+n][k] = W_w[k][n], bf16.
// ------------------------------------------------------------------
__global__ __launch_bounds__(256) void transpose_w_kernel(
    const void* __restrict__ Wq, const void* __restrict__ Wk,
    const void* __restrict__ Wv, const unsigned int* __restrict__ xw,
    unsigned short* __restrict__ Wt) {
    __shared__ int sflag;
    __shared__ unsigned short ts[64][68];
    const int tid = threadIdx.x;
    const int isf32 = block_detect_f32(xw, tid, &sflag);
    const int w = blockIdx.x >> 4, kt = blockIdx.x & 15;
    const void* W = (w == 0) ? Wq : (w == 1) ? Wk : Wv;
    const int kk = tid >> 4, nn = (tid & 15) * 4;
#pragma unroll
    for (int j = 0; j < 4; ++j) {
        int k = kk + j * 16;
        if (isf32) {
            float4 f = *(const float4*)((const float*)W + (size_t)(kt * 64 + k) * 64 + nn);
            ts[k][nn + 0] = f2bf(f.x); ts[k][nn + 1] = f2bf(f.y);
            ts[k][nn + 2] = f2bf(f.z); ts[k][nn + 3] = f2bf(f.w);
        } else {
            *(uint2*)&ts[k][nn] =
                *(const uint2*)((const unsigned short*)W + (size_t)(kt * 64 + k) * 64 + nn);
        }
    }
    __syncthreads();
    const int n = tid >> 2, k0 = (tid & 3) * 16;
    unsigned short tmp[16];
#pragma unroll
    for (int j = 0; j < 16; ++j) tmp[j] = ts[k0 + j][n];
    unsigned short* dst = Wt + (size_t)(w * 64 + n) * 1024 + kt * 64 + k0;
    *(uint4*)(dst + 0) = *(uint4*)&tmp[0];
    *(uint4*)(dst + 8) = *(uint4*)&tmp[8];
}

// ------------------------------------------------------------------
// Fused QKV projection v8: REVERT to single-buffer LDS (23 KB -> 6
// blocks/CU; R1's explicit dbuf cut occupancy to 2 blocks/CU and
// regressed 40->70 us — TLP, not source pipelining, hides latency
// here). NEW: 2-deep x register prefetch (pxA/pxB, statically indexed
// 2-step loop per rule #20): ldx(it+2) issued after the drain barrier
// gives x's ~900cy HBM latency 2 full iterations of cover (the old
// 1-deep gap was ~300-500cy -> writeX stalled every iter).
// Grid (256,2): nh-partner blocks are 256 apart = same XCD under
// round-robin -> second x read is an L2 hit.
// ------------------------------------------------------------------
#define XR 72      /* x LDS row stride in bf16 elems (144 B) */
#define WROWC 9    /* W LDS row = 9 chunks = 144 B (128 payload) */

__global__ __launch_bounds__(256, 4) void proj_kernel(
    const void* __restrict__ xraw, const unsigned short* __restrict__ Wt,
    unsigned short* __restrict__ qbuf, unsigned short* __restrict__ kbuf,
    unsigned short* __restrict__ vtbuf) {
    __shared__ int sflag;
    __shared__ __align__(16) unsigned short xs[64 * XR];            // 9216 B
    __shared__ __align__(16) unsigned char wlds[96 * WROWC * 16];   // 13824 B

    const int tid = threadIdx.x;
    const int isf32 = block_detect_f32((const unsigned int*)xraw, tid, &sflag);
    const int m0 = blockIdx.x * 64;
    const int nh = blockIdx.y;                 // N cols nh*96 .. nh*96+95
    const int wave = tid >> 6, lane = tid & 63, quad = lane >> 4, l15 = lane & 15;
    const int rw = wave & 1, cw = wave >> 1;   // rows rw*32.., cols cw*48..

    const float* xf = (const float*)xraw;
    const unsigned short* xb = (const unsigned short*)xraw;
    const unsigned char* wg = (const unsigned char*)Wt;

    // W staging: 96 rows * 9 chunks = 864 chunks, guarded
    const unsigned char* wsrc[4];
    unsigned int wdst[4];
    int nw = 0;
#pragma unroll
    for (int j = 0; j < 4; ++j) {
        int c = (wave + 4 * j) * 64 + lane;
        if (c < 864) {
            int R = c / WROWC, cc = c % WROWC;
            int ccu = (cc > 7) ? 0 : cc;
            wsrc[nw] = wg + (size_t)(nh * 96 + R) * 2048 + ccu * 16;
            wdst[nw] = c * 16;
            ++nw;
        }
    }

    // x reg staging role: thread -> row xr (0..63), 16 cols at xc
    const int xr = tid >> 2, xc = (tid & 3) * 16;

    auto ldx = [&](int k0, float4 (&px)[4], uint4 (&pxb)[2]) {
        if (isf32) {
            const float* g = xf + (size_t)(m0 + xr) * DIN + k0 + xc;
#pragma unroll
            for (int j = 0; j < 4; ++j) px[j] = *(const float4*)(g + j * 4);
        } else {
            const unsigned short* g = xb + (size_t)(m0 + xr) * DIN + k0 + xc;
            pxb[0] = *(const uint4*)(g + 0);
            pxb[1] = *(const uint4*)(g + 8);
        }
    };
    auto writeX = [&](float4 (&px)[4], uint4 (&pxb)[2]) {
        if (isf32) {
            unsigned short t[16];
#pragma unroll
            for (int j = 0; j < 4; ++j) {
                t[j * 4 + 0] = f2bf(px[j].x); t[j * 4 + 1] = f2bf(px[j].y);
                t[j * 4 + 2] = f2bf(px[j].z); t[j * 4 + 3] = f2bf(px[j].w);
            }
            *(uint4*)&xs[xr * XR + xc + 0] = *(uint4*)&t[0];
            *(uint4*)&xs[xr * XR + xc + 8] = *(uint4*)&t[8];
        } else {
            *(uint4*)&xs[xr * XR + xc + 0] = pxb[0];
            *(uint4*)&xs[xr * XR + xc + 8] = pxb[1];
        }
    };

    f32x4 acc[2][3];
#pragma unroll
    for (int rt = 0; rt < 2; ++rt)
#pragma unroll
        for (int ct = 0; ct < 3; ++ct)
            acc[rt][ct] = (f32x4){0.f, 0.f, 0.f, 0.f};

    auto compute = [&]() {
#pragma unroll
        for (int ks = 0; ks < 2; ++ks) {
            bf16x8 a[2], b[3];
#pragma unroll
            for (int rt = 0; rt < 2; ++rt)
                a[rt] = *(const bf16x8*)
                    &xs[(rw * 32 + rt * 16 + l15) * XR + ks * 32 + quad * 8];
#pragma unroll
            for (int ct = 0; ct < 3; ++ct)
                b[ct] = *(const bf16x8*)
                    &wlds[(cw * 48 + ct * 16 + l15) * (WROWC * 16) + ks * 64 + quad * 16];
#pragma unroll
            for (int rt = 0; rt < 2; ++rt)
#pragma unroll
                for (int ct = 0; ct < 3; ++ct)
                    acc[rt][ct] = __builtin_amdgcn_mfma_f32_16x16x32_bf16(
                        a[rt], b[ct], acc[rt][ct], 0, 0, 0);
        }
    };

    // one K-step; px/pxb are the buffer CONSUMED this iter (and refilled
    // for iter it+2 — 2-deep prefetch, statically indexed A/B)
    auto step = [&](int it, float4 (&px)[4], uint4 (&pxb)[2]) {
        __syncthreads();                     // prev compute done reading LDS
        writeX(px, pxb);
        const size_t off = (size_t)it * 128;
        for (int j = 0; j < nw; ++j) async16(&wlds[wdst[j]], wsrc[j] + off);
        __syncthreads();                     // staging visible (drains DMA)
        if (it < 14) ldx((it + 2) * 64, px, pxb);
        compute();
    };

    float4 pxA[4], pxB[4];
    uint4  pbA[2], pbB[2];
    ldx(0, pxA, pbA);
    ldx(64, pxB, pbB);

    for (int itp = 0; itp < 16; itp += 2) {
        step(itp + 0, pxA, pbA);
        step(itp + 1, pxB, pbB);
    }

    // epilogue: D[row=quad*4+reg][col=l15]
#pragma unroll
    for (int rt = 0; rt < 2; ++rt)
#pragma unroll
        for (int ct = 0; ct < 3; ++ct) {
            int n = nh * 96 + cw * 48 + ct * 16 + l15;
            int wsel = n >> 6, nn = n & 63;
#pragma unroll
            for (int reg = 0; reg < 4; ++reg) {
                int m = m0 + rw * 32 + rt * 16 + quad * 4 + reg;
                unsigned short bv = f2bf(acc[rt][ct][reg]);
                if (wsel == 0)      qbuf[(size_t)m * HH + nn] = bv;
                else if (wsel == 1) kbuf[(size_t)m * HH + nn] = bv;
                else {
                    int bb = m >> 11, t = m & 2047;
                    vtbuf[((size_t)bb * HH + nn) * TT + t] = bv;
                }
            }
        }
}

// ------------------------------------------------------------------
// Split-column flash attention, FIXED exponent shift (no online max;
// partials are directly summable). Linear grid 640: b = bid&7 pins
// batch b to XCD b (K/Q/VT slice L2-resident). T14 async-STAGE split:
// next K/V tile's global loads issued right after QK^T. T5 setprio
// around MFMA clusters (independent blocks at different phases -> the
// regime where setprio measured +4-7%).
// ------------------------------------------------------------------
__global__ __launch_bounds__(256, 4) void attn_kernel(
    const unsigned short* __restrict__ rowbuf,  // k-proj [b][t][h]
    const unsigned short* __restrict__ colbuf,  // q-proj [b][s][h]
    const unsigned short* __restrict__ vtbuf,   // [b][h][s]
    float* __restrict__ O_part,                 // [slot][64][64]
    float* __restrict__ l_part) {               // [slot][64]

    __shared__ __align__(16) unsigned short Qr_s[64][72];
    __shared__ __align__(16) unsigned short Kc_s[64][72];
    __shared__ __align__(16) unsigned short Vt_s[64][72];
    __shared__ __align__(16) unsigned short P_s[4][16][72];

    const int tid  = threadIdx.x;
    const int bid  = blockIdx.x;   // 0..639
    const int b    = bid & 7;      // XCD-pinned batch
    const int bx   = bid >> 3;     // 0..79
    int rt, ch;
    if (bx < 8)       { rt = bx;                 ch = 0; }
    else if (bx < 24) { rt = 8 + ((bx - 8) >> 1);  ch = (bx - 8) & 1; }
    else if (bx < 48) { rt = 16 + (bx - 24) / 3;   ch = (bx - 24) % 3; }
    else              { rt = 24 + ((bx - 48) >> 2); ch = (bx - 48) & 3; }
    const int nct = min(8, rt + 1 - ch * 8);
    const int t0 = rt * 64;
    const int slot = b * 80 + bx;

    const int wave = tid >> 6, lane = tid & 63, quad = lane >> 4, l15 = lane & 15;
    const int sr = tid >> 2, sc = (tid & 3) * 16;

    {
        const uint4* g = (const uint4*)(rowbuf + ((size_t)b * TT + t0 + sr) * HH + sc);
        *(uint4*)&Qr_s[sr][sc + 0] = g[0];
        *(uint4*)&Qr_s[sr][sc + 8] = g[1];
    }

    f32x4 o[4];
#pragma unroll
    for (int c = 0; c < 4; ++c) o[c] = (f32x4){0.f, 0.f, 0.f, 0.f};
    float ls[4] = {0.f, 0.f, 0.f, 0.f};

    const float SCL2 = 0.125f * 1.4426950408889634f;  // H^-0.5 * log2(e)

    // register prefetch of K/V tile (16 VGPRs, consumed at loop top)
    uint4 pk0, pk1, pv0, pv1;
    auto loadKV = [&](int i) {
        const int s0 = (ch * 8 + i) * 64;
        const uint4* gk = (const uint4*)(colbuf + ((size_t)b * TT + s0 + sr) * HH + sc);
        pk0 = gk[0]; pk1 = gk[1];
        const uint4* gv = (const uint4*)(vtbuf + ((size_t)b * HH + sr) * TT + s0 + sc);
        pv0 = gv[0]; pv1 = gv[1];
    };
    loadKV(0);

    for (int i = 0; i < nct; ++i) {
        const int stc = ch * 8 + i;
        const int s0 = stc * 64;
        *(uint4*)&Kc_s[sr][sc + 0] = pk0;
        *(uint4*)&Kc_s[sr][sc + 8] = pk1;
        *(uint4*)&Vt_s[sr][sc + 0] = pv0;
        *(uint4*)&Vt_s[sr][sc + 8] = pv1;
        __syncthreads();

        f32x4 scf[4];
#pragma unroll
        for (int c = 0; c < 4; ++c) scf[c] = (f32x4){0.f, 0.f, 0.f, 0.f};
        __builtin_amdgcn_s_setprio(1);
#pragma unroll
        for (int ks = 0; ks < 2; ++ks) {
            bf16x8 a = *(const bf16x8*)&Qr_s[wave * 16 + l15][ks * 32 + quad * 8];
#pragma unroll
            for (int c = 0; c < 4; ++c) {
                bf16x8 bb = *(const bf16x8*)&Kc_s[c * 16 + l15][ks * 32 + quad * 8];
                scf[c] = __builtin_amdgcn_mfma_f32_16x16x32_bf16(a, bb, scf[c], 0, 0, 0);
            }
        }
        __builtin_amdgcn_s_setprio(0);

        // issue next tile's global loads NOW; latency hides under softmax+PV
        if (i + 1 < nct) loadKV(i + 1);

        const bool diag = (stc == rt);
#pragma unroll
        for (int r = 0; r < 4; ++r) {
            const int tg = t0 + wave * 16 + quad * 4 + r;
#pragma unroll
            for (int c = 0; c < 4; ++c) {
                float arg = fmaf(scf[c][r], SCL2, -30.f);
                if (diag && (s0 + c * 16 + l15) > tg) arg = -200.f;
                float p = __builtin_amdgcn_exp2f(arg);
                P_s[wave][quad * 4 + r][c * 16 + l15] = f2bf(p);
                ls[r] += p;
            }
        }
        // P_s is per-wave: intra-wave LDS RAW, compiler lgkmcnt suffices.
        __builtin_amdgcn_s_setprio(1);
#pragma unroll
        for (int ks = 0; ks < 2; ++ks) {
            bf16x8 ap = *(const bf16x8*)&P_s[wave][l15][ks * 32 + quad * 8];
#pragma unroll
            for (int c = 0; c < 4; ++c) {
                bf16x8 bv = *(const bf16x8*)&Vt_s[c * 16 + l15][ks * 32 + quad * 8];
                o[c] = __builtin_amdgcn_mfma_f32_16x16x32_bf16(ap, bv, o[c], 0, 0, 0);
            }
        }
        __builtin_amdgcn_s_setprio(0);
        __syncthreads();   // Kc/Vt consumed; safe to restage
    }

    // per-row l: reduce over the 16 l15 lanes (once, at the end)
#pragma unroll
    for (int r = 0; r < 4; ++r) {
#pragma unroll
        for (int off = 1; off < 16; off <<= 1) ls[r] += __shfl_xor(ls[r], off);
    }
    if (l15 == 0) {
#pragma unroll
        for (int r = 0; r < 4; ++r)
            l_part[(size_t)slot * 64 + wave * 16 + quad * 4 + r] = ls[r];
    }
#pragma unroll
    for (int c = 0; c < 4; ++c)
#pragma unroll
        for (int r = 0; r < 4; ++r)
            O_part[(size_t)slot * 4096 + (wave * 16 + quad * 4 + r) * 64 + c * 16 + l15] = o[c][r];
}

// ------------------------------------------------------------------
// Combine partials: out = (sum O_part) / (sum l_part). Linear grid
// 256, b = bid&7 -> same-XCD L2 reuse of O_part written by attn.
// ------------------------------------------------------------------
__global__ __launch_bounds__(256) void combine_kernel(
    const float* __restrict__ O_part, const float* __restrict__ l_part,
    const unsigned int* __restrict__ xw, void* __restrict__ outraw) {
    __shared__ int sflag;
    const int tid = threadIdx.x;
    const int isf32 = block_detect_f32(xw, tid, &sflag);
    const int bid = blockIdx.x;
    const int b = bid & 7, rt = bid >> 3;
    const int nch = rt / 8 + 1;
    const int off = (rt < 8) ? rt : (rt < 16) ? 8 + 2 * (rt - 8)
                   : (rt < 24) ? 24 + 3 * (rt - 16) : 48 + 4 * (rt - 24);
    const int slot0 = b * 80 + off;

    const int row = tid >> 2, cb = (tid & 3) * 16;
    f32x4 a[4];
#pragma unroll
    for (int q = 0; q < 4; ++q) a[q] = (f32x4){0.f, 0.f, 0.f, 0.f};
    float l = 0.f;
    for (int j = 0; j < nch; ++j) {
        const f32x4* p = (const f32x4*)(O_part + (size_t)(slot0 + j) * 4096 + row * 64 + cb);
#pragma unroll
        for (int q = 0; q < 4; ++q) a[q] += p[q];
        l += l_part[(size_t)(slot0 + j) * 64 + row];
    }
    const float inv = 1.f / l;
    const size_t base = ((size_t)b * TT + rt * 64 + row) * HH + cb;
    if (isf32) {
        float* outf = (float*)outraw;
#pragma unroll
        for (int q = 0; q < 4; ++q) {
            f32x4 v = a[q] * inv;
            *(f32x4*)(outf + base + q * 4) = v;
        }
    } else {
        unsigned short h[16];
#pragma unroll
        for (int q = 0; q < 4; ++q)
#pragma unroll
            for (int e = 0; e < 4; ++e) h[q * 4 + e] = f2bf(a[q][e] * inv);
        unsigned short* outb = (unsigned short*)outraw;
        *(uint4*)(outb + base + 0) = *(uint4*)&h[0];
        *(uint4*)(outb + base + 8) = *(uint4*)&h[8];
    }
}

extern "C" void kernel_launch(void* const* d_in, const int* in_sizes, int n_in,
                              void* d_out, int out_size, void* d_ws, size_t ws_size,
                              hipStream_t stream) {
    const void* x  = d_in[0];
    const void* Wq = d_in[1];
    const void* Wk = d_in[2];
    const void* Wv = d_in[3];
    unsigned short* ws = (unsigned short*)d_ws;

    unsigned short* qbuf  = ws;                          // 2 MB
    unsigned short* kbuf  = ws + (size_t)MM * HH;        // 2 MB
    unsigned short* vtbuf = ws + (size_t)2 * MM * HH;    // 2 MB
    unsigned short* wtbuf = ws + (size_t)3 * MM * HH;    // 384 KB
    float* O_part = (float*)(ws + (size_t)3 * MM * HH + 3 * 65536);  // 10.5 MB
    float* l_part = O_part + (size_t)640 * 4096;                      // 164 KB

    hipLaunchKernelGGL(transpose_w_kernel, dim3(48), dim3(256), 0, stream,
                       Wq, Wk, Wv, (const unsigned int*)x, wtbuf);
    hipLaunchKernelGGL(proj_kernel, dim3(256, 2), dim3(256), 0, stream,
                       x, wtbuf, qbuf, kbuf, vtbuf);
    hipLaunchKernelGGL(attn_kernel, dim3(640), dim3(256), 0, stream,
                       kbuf, qbuf, vtbuf, O_part, l_part);
    hipLaunchKernelGGL(combine_kernel, dim3(256), dim3(256), 0, stream,
                       O_part, l_part, (const unsigned int*)x, d_out);
}

// Round 3
// 144.684 us; speedup vs baseline: 1.2124x; 1.0680x over previous
//
#include <hip/hip_runtime.h>

typedef __bf16 bf16_t;
typedef bf16_t bf16x8 __attribute__((ext_vector_type(8)));
typedef float f32x4 __attribute__((ext_vector_type(4)));

#define NB 8
#define TT 2048
#define DIN 1024
#define HH 64
#define MM (NB * TT)

__device__ __forceinline__ unsigned short f2bf(float f) {
    unsigned int u = __float_as_uint(f);
    u += 0x7fffu + ((u >> 16) & 1u);   // round-to-nearest-even
    return (unsigned short)(u >> 16);
}

// async global->LDS, 16B per lane. LDS dest = base + lane*16 (linear);
// global src may be per-lane (16B-aligned). Exec-masked.
__device__ __forceinline__ void async16(void* l, const void* g) {
    __builtin_amdgcn_global_load_lds(
        (const __attribute__((address_space(1))) unsigned int*)g,
        (__attribute__((address_space(3))) unsigned int*)l, 16, 0, 0);
}

// Per-block dtype probe: low-bf16 exponent field of x words.
// fp32 data -> ~20% in range; bf16 -> ~100%. Returns 1 if fp32.
__device__ __forceinline__ int block_detect_f32(const unsigned int* __restrict__ xw,
                                                int tid, int* sflag) {
    if (tid < 64) {
        unsigned int u = xw[tid];
        unsigned int e = (u >> 7) & 0xFFu;
        unsigned long long m = __ballot(e >= 100u && e <= 150u);
        if (tid == 0) *sflag = (__popcll(m) < 48) ? 1 : 0;
    }
    __syncthreads();
    return *sflag;
}

// ------------------------------------------------------------------
// LDS-tiled W transpose: Wt[w*64+n][k] = W_w[k][n], bf16.
// ------------------------------------------------------------------
__global__ __launch_bounds__(256) void transpose_w_kernel(
    const void* __restrict__ Wq, const void* __restrict__ Wk,
    const void* __restrict__ Wv, const unsigned int* __restrict__ xw,
    unsigned short* __restrict__ Wt) {
    __shared__ int sflag;
    __shared__ unsigned short ts[64][68];
    const int tid = threadIdx.x;
    const int isf32 = block_detect_f32(xw, tid, &sflag);
    const int w = blockIdx.x >> 4, kt = blockIdx.x & 15;
    const void* W = (w == 0) ? Wq : (w == 1) ? Wk : Wv;
    const int kk = tid >> 4, nn = (tid & 15) * 4;
#pragma unroll
    for (int j = 0; j < 4; ++j) {
        int k = kk + j * 16;
        if (isf32) {
            float4 f = *(const float4*)((const float*)W + (size_t)(kt * 64 + k) * 64 + nn);
            ts[k][nn + 0] = f2bf(f.x); ts[k][nn + 1] = f2bf(f.y);
            ts[k][nn + 2] = f2bf(f.z); ts[k][nn + 3] = f2bf(f.w);
        } else {
            *(uint2*)&ts[k][nn] =
                *(const uint2*)((const unsigned short*)W + (size_t)(kt * 64 + k) * 64 + nn);
        }
    }
    __syncthreads();
    const int n = tid >> 2, k0 = (tid & 3) * 16;
    unsigned short tmp[16];
#pragma unroll
    for (int j = 0; j < 16; ++j) tmp[j] = ts[k0 + j][n];
    unsigned short* dst = Wt + (size_t)(w * 64 + n) * 1024 + kt * 64 + k0;
    *(uint4*)(dst + 0) = *(uint4*)&tmp[0];
    *(uint4*)(dst + 8) = *(uint4*)&tmp[8];
}

// ------------------------------------------------------------------
// Fused QKV projection v9: R0 inner structure (single-buffer LDS,
// 1-deep x prefetch, launch_bounds(256,2)) — the verified-fast
// variant — but RE-TILED N 96->48 so grid = (256,4) = 1024 blocks =
// 4 blocks/CU = 16 waves/CU (50% occupancy; was grid-capped at 25%).
// Proj is latency-bound (R2: hbm 900 GB/s, MfmaUtil 4%) — TLP is the
// lever, not pipelining (R1/R2 lesson). Blocks (m, nh=0..3) are 256
// apart -> same CU under round-robin: 4-way x-stripe reuse is L1-hit.
// Wave-tile 16x48: per ks 1 A + 3 B ds_read_b128 -> 3 MFMA.
// LDS: xs 9216 B + wlds 6912 B = 16.1 KB.
// ------------------------------------------------------------------
#define XR 72      /* x LDS row stride in bf16 elems (144 B) */
#define WROWC 9    /* W LDS row = 9 chunks = 144 B (128 payload) */
#define PN 48      /* N cols per proj block */

__global__ __launch_bounds__(256, 2) void proj_kernel(
    const void* __restrict__ xraw, const unsigned short* __restrict__ Wt,
    unsigned short* __restrict__ qbuf, unsigned short* __restrict__ kbuf,
    unsigned short* __restrict__ vtbuf) {
    __shared__ int sflag;
    __shared__ __align__(16) unsigned short xs[64 * XR];            // 9216 B
    __shared__ __align__(16) unsigned char wlds[PN * WROWC * 16];   // 6912 B

    const int tid = threadIdx.x;
    const int isf32 = block_detect_f32((const unsigned int*)xraw, tid, &sflag);
    const int m0 = blockIdx.x * 64;
    const int nh = blockIdx.y;                 // N cols nh*48 .. nh*48+47
    const int wave = tid >> 6, lane = tid & 63, quad = lane >> 4, l15 = lane & 15;

    const float* xf = (const float*)xraw;
    const unsigned short* xb = (const unsigned short*)xraw;
    const unsigned char* wg = (const unsigned char*)Wt;

    // W staging: 48 rows * 9 chunks = 432 chunks, guarded
    const unsigned char* wsrc[2];
    unsigned int wdst[2];
    int nw = 0;
#pragma unroll
    for (int j = 0; j < 2; ++j) {
        int c = (wave + 4 * j) * 64 + lane;
        if (c < PN * WROWC) {
            int R = c / WROWC, cc = c % WROWC;
            int ccu = (cc > 7) ? 0 : cc;
            wsrc[nw] = wg + (size_t)(nh * PN + R) * 2048 + ccu * 16;
            wdst[nw] = c * 16;
            ++nw;
        }
    }

    // x reg staging role: thread -> row xr (0..63), 16 cols at xc
    const int xr = tid >> 2, xc = (tid & 3) * 16;
    float4 px[4];
    uint4  pxb[2];
    auto ldx = [&](int k0) {
        if (isf32) {
            const float* g = xf + (size_t)(m0 + xr) * DIN + k0 + xc;
#pragma unroll
            for (int j = 0; j < 4; ++j) px[j] = *(const float4*)(g + j * 4);
        } else {
            const unsigned short* g = xb + (size_t)(m0 + xr) * DIN + k0 + xc;
            pxb[0] = *(const uint4*)(g + 0);
            pxb[1] = *(const uint4*)(g + 8);
        }
    };

    f32x4 acc[3];
#pragma unroll
    for (int ct = 0; ct < 3; ++ct) acc[ct] = (f32x4){0.f, 0.f, 0.f, 0.f};

    ldx(0);
    size_t woff = 0;
    for (int it = 0; it < 16; ++it) {
        __syncthreads();   // previous compute done reading LDS
        if (isf32) {
            unsigned short t[16];
#pragma unroll
            for (int j = 0; j < 4; ++j) {
                t[j * 4 + 0] = f2bf(px[j].x); t[j * 4 + 1] = f2bf(px[j].y);
                t[j * 4 + 2] = f2bf(px[j].z); t[j * 4 + 3] = f2bf(px[j].w);
            }
            *(uint4*)&xs[xr * XR + xc + 0] = *(uint4*)&t[0];
            *(uint4*)&xs[xr * XR + xc + 8] = *(uint4*)&t[8];
        } else {
            *(uint4*)&xs[xr * XR + xc + 0] = pxb[0];
            *(uint4*)&xs[xr * XR + xc + 8] = pxb[1];
        }
        for (int j = 0; j < nw; ++j) async16(&wlds[wdst[j]], wsrc[j] + woff);
        woff += 128;
        __syncthreads();   // staging visible (barrier drains DMA)

        if (it < 15) ldx((it + 1) * 64);   // overlap next x load with compute

#pragma unroll
        for (int ks = 0; ks < 2; ++ks) {
            bf16x8 a = *(const bf16x8*)&xs[(wave * 16 + l15) * XR + ks * 32 + quad * 8];
            bf16x8 b[3];
#pragma unroll
            for (int ct = 0; ct < 3; ++ct)
                b[ct] = *(const bf16x8*)
                    &wlds[(ct * 16 + l15) * (WROWC * 16) + ks * 64 + quad * 16];
#pragma unroll
            for (int ct = 0; ct < 3; ++ct)
                acc[ct] = __builtin_amdgcn_mfma_f32_16x16x32_bf16(
                    a, b[ct], acc[ct], 0, 0, 0);
        }
    }

    // epilogue: D[row=quad*4+reg][col=l15]; wave owns rows wave*16..+15
#pragma unroll
    for (int ct = 0; ct < 3; ++ct) {
        int n = nh * PN + ct * 16 + l15;
        int wsel = n >> 6, nn = n & 63;
#pragma unroll
        for (int reg = 0; reg < 4; ++reg) {
            int m = m0 + wave * 16 + quad * 4 + reg;
            unsigned short bv = f2bf(acc[ct][reg]);
            if (wsel == 0)      qbuf[(size_t)m * HH + nn] = bv;
            else if (wsel == 1) kbuf[(size_t)m * HH + nn] = bv;
            else {
                int bb = m >> 11, t = m & 2047;
                vtbuf[((size_t)bb * HH + nn) * TT + t] = bv;
            }
        }
    }
}

// ------------------------------------------------------------------
// Split-column flash attention, FIXED exponent shift (no online max;
// partials are directly summable). Linear grid 640: b = bid&7 pins
// batch b to XCD b (K/Q/VT slice L2-resident). T14 async-STAGE split:
// next K/V tile's global loads issued right after QK^T. T5 setprio
// around MFMA clusters.
// ------------------------------------------------------------------
__global__ __launch_bounds__(256, 4) void attn_kernel(
    const unsigned short* __restrict__ rowbuf,  // k-proj [b][t][h]
    const unsigned short* __restrict__ colbuf,  // q-proj [b][s][h]
    const unsigned short* __restrict__ vtbuf,   // [b][h][s]
    float* __restrict__ O_part,                 // [slot][64][64]
    float* __restrict__ l_part) {               // [slot][64]

    __shared__ __align__(16) unsigned short Qr_s[64][72];
    __shared__ __align__(16) unsigned short Kc_s[64][72];
    __shared__ __align__(16) unsigned short Vt_s[64][72];
    __shared__ __align__(16) unsigned short P_s[4][16][72];

    const int tid  = threadIdx.x;
    const int bid  = blockIdx.x;   // 0..639
    const int b    = bid & 7;      // XCD-pinned batch
    const int bx   = bid >> 3;     // 0..79
    int rt, ch;
    if (bx < 8)       { rt = bx;                 ch = 0; }
    else if (bx < 24) { rt = 8 + ((bx - 8) >> 1);  ch = (bx - 8) & 1; }
    else if (bx < 48) { rt = 16 + (bx - 24) / 3;   ch = (bx - 24) % 3; }
    else              { rt = 24 + ((bx - 48) >> 2); ch = (bx - 48) & 3; }
    const int nct = min(8, rt + 1 - ch * 8);
    const int t0 = rt * 64;
    const int slot = b * 80 + bx;

    const int wave = tid >> 6, lane = tid & 63, quad = lane >> 4, l15 = lane & 15;
    const int sr = tid >> 2, sc = (tid & 3) * 16;

    {
        const uint4* g = (const uint4*)(rowbuf + ((size_t)b * TT + t0 + sr) * HH + sc);
        *(uint4*)&Qr_s[sr][sc + 0] = g[0];
        *(uint4*)&Qr_s[sr][sc + 8] = g[1];
    }

    f32x4 o[4];
#pragma unroll
    for (int c = 0; c < 4; ++c) o[c] = (f32x4){0.f, 0.f, 0.f, 0.f};
    float ls[4] = {0.f, 0.f, 0.f, 0.f};

    const float SCL2 = 0.125f * 1.4426950408889634f;  // H^-0.5 * log2(e)

    // register prefetch of K/V tile (16 VGPRs, consumed at loop top)
    uint4 pk0, pk1, pv0, pv1;
    auto loadKV = [&](int i) {
        const int s0 = (ch * 8 + i) * 64;
        const uint4* gk = (const uint4*)(colbuf + ((size_t)b * TT + s0 + sr) * HH + sc);
        pk0 = gk[0]; pk1 = gk[1];
        const uint4* gv = (const uint4*)(vtbuf + ((size_t)b * HH + sr) * TT + s0 + sc);
        pv0 = gv[0]; pv1 = gv[1];
    };
    loadKV(0);

    for (int i = 0; i < nct; ++i) {
        const int stc = ch * 8 + i;
        const int s0 = stc * 64;
        *(uint4*)&Kc_s[sr][sc + 0] = pk0;
        *(uint4*)&Kc_s[sr][sc + 8] = pk1;
        *(uint4*)&Vt_s[sr][sc + 0] = pv0;
        *(uint4*)&Vt_s[sr][sc + 8] = pv1;
        __syncthreads();

        f32x4 scf[4];
#pragma unroll
        for (int c = 0; c < 4; ++c) scf[c] = (f32x4){0.f, 0.f, 0.f, 0.f};
        __builtin_amdgcn_s_setprio(1);
#pragma unroll
        for (int ks = 0; ks < 2; ++ks) {
            bf16x8 a = *(const bf16x8*)&Qr_s[wave * 16 + l15][ks * 32 + quad * 8];
#pragma unroll
            for (int c = 0; c < 4; ++c) {
                bf16x8 bb = *(const bf16x8*)&Kc_s[c * 16 + l15][ks * 32 + quad * 8];
                scf[c] = __builtin_amdgcn_mfma_f32_16x16x32_bf16(a, bb, scf[c], 0, 0, 0);
            }
        }
        __builtin_amdgcn_s_setprio(0);

        // issue next tile's global loads NOW; latency hides under softmax+PV
        if (i + 1 < nct) loadKV(i + 1);

        const bool diag = (stc == rt);
#pragma unroll
        for (int r = 0; r < 4; ++r) {
            const int tg = t0 + wave * 16 + quad * 4 + r;
#pragma unroll
            for (int c = 0; c < 4; ++c) {
                float arg = fmaf(scf[c][r], SCL2, -30.f);
                if (diag && (s0 + c * 16 + l15) > tg) arg = -200.f;
                float p = __builtin_amdgcn_exp2f(arg);
                P_s[wave][quad * 4 + r][c * 16 + l15] = f2bf(p);
                ls[r] += p;
            }
        }
        // P_s is per-wave: intra-wave LDS RAW, compiler lgkmcnt suffices.
        __builtin_amdgcn_s_setprio(1);
#pragma unroll
        for (int ks = 0; ks < 2; ++ks) {
            bf16x8 ap = *(const bf16x8*)&P_s[wave][l15][ks * 32 + quad * 8];
#pragma unroll
            for (int c = 0; c < 4; ++c) {
                bf16x8 bv = *(const bf16x8*)&Vt_s[c * 16 + l15][ks * 32 + quad * 8];
                o[c] = __builtin_amdgcn_mfma_f32_16x16x32_bf16(ap, bv, o[c], 0, 0, 0);
            }
        }
        __builtin_amdgcn_s_setprio(0);
        __syncthreads();   // Kc/Vt consumed; safe to restage
    }

    // per-row l: reduce over the 16 l15 lanes (once, at the end)
#pragma unroll
    for (int r = 0; r < 4; ++r) {
#pragma unroll
        for (int off = 1; off < 16; off <<= 1) ls[r] += __shfl_xor(ls[r], off);
    }
    if (l15 == 0) {
#pragma unroll
        for (int r = 0; r < 4; ++r)
            l_part[(size_t)slot * 64 + wave * 16 + quad * 4 + r] = ls[r];
    }
#pragma unroll
    for (int c = 0; c < 4; ++c)
#pragma unroll
        for (int r = 0; r < 4; ++r)
            O_part[(size_t)slot * 4096 + (wave * 16 + quad * 4 + r) * 64 + c * 16 + l15] = o[c][r];
}

// ------------------------------------------------------------------
// Combine partials: out = (sum O_part) / (sum l_part). Linear grid
// 256, b = bid&7 -> same-XCD L2 reuse of O_part written by attn.
// ------------------------------------------------------------------
__global__ __launch_bounds__(256) void combine_kernel(
    const float* __restrict__ O_part, const float* __restrict__ l_part,
    const unsigned int* __restrict__ xw, void* __restrict__ outraw) {
    __shared__ int sflag;
    const int tid = threadIdx.x;
    const int isf32 = block_detect_f32(xw, tid, &sflag);
    const int bid = blockIdx.x;
    const int b = bid & 7, rt = bid >> 3;
    const int nch = rt / 8 + 1;
    const int off = (rt < 8) ? rt : (rt < 16) ? 8 + 2 * (rt - 8)
                   : (rt < 24) ? 24 + 3 * (rt - 16) : 48 + 4 * (rt - 24);
    const int slot0 = b * 80 + off;

    const int row = tid >> 2, cb = (tid & 3) * 16;
    f32x4 a[4];
#pragma unroll
    for (int q = 0; q < 4; ++q) a[q] = (f32x4){0.f, 0.f, 0.f, 0.f};
    float l = 0.f;
    for (int j = 0; j < nch; ++j) {
        const f32x4* p = (const f32x4*)(O_part + (size_t)(slot0 + j) * 4096 + row * 64 + cb);
#pragma unroll
        for (int q = 0; q < 4; ++q) a[q] += p[q];
        l += l_part[(size_t)(slot0 + j) * 64 + row];
    }
    const float inv = 1.f / l;
    const size_t base = ((size_t)b * TT + rt * 64 + row) * HH + cb;
    if (isf32) {
        float* outf = (float*)outraw;
#pragma unroll
        for (int q = 0; q < 4; ++q) {
            f32x4 v = a[q] * inv;
            *(f32x4*)(outf + base + q * 4) = v;
        }
    } else {
        unsigned short h[16];
#pragma unroll
        for (int q = 0; q < 4; ++q)
#pragma unroll
            for (int e = 0; e < 4; ++e) h[q * 4 + e] = f2bf(a[q][e] * inv);
        unsigned short* outb = (unsigned short*)outraw;
        *(uint4*)(outb + base + 0) = *(uint4*)&h[0];
        *(uint4*)(outb + base + 8) = *(uint4*)&h[8];
    }
}

extern "C" void kernel_launch(void* const* d_in, const int* in_sizes, int n_in,
                              void* d_out, int out_size, void* d_ws, size_t ws_size,
                              hipStream_t stream) {
    const void* x  = d_in[0];
    const void* Wq = d_in[1];
    const void* Wk = d_in[2];
    const void* Wv = d_in[3];
    unsigned short* ws = (unsigned short*)d_ws;

    unsigned short* qbuf  = ws;                          // 2 MB
    unsigned short* kbuf  = ws + (size_t)MM * HH;        // 2 MB
    unsigned short* vtbuf = ws + (size_t)2 * MM * HH;    // 2 MB
    unsigned short* wtbuf = ws + (size_t)3 * MM * HH;    // 384 KB
    float* O_part = (float*)(ws + (size_t)3 * MM * HH + 3 * 65536);  // 10.5 MB
    float* l_part = O_part + (size_t)640 * 4096;                      // 164 KB

    hipLaunchKernelGGL(transpose_w_kernel, dim3(48), dim3(256), 0, stream,
                       Wq, Wk, Wv, (const unsigned int*)x, wtbuf);
    hipLaunchKernelGGL(proj_kernel, dim3(256, 4), dim3(256), 0, stream,
                       x, wtbuf, qbuf, kbuf, vtbuf);
    hipLaunchKernelGGL(attn_kernel, dim3(640), dim3(256), 0, stream,
                       kbuf, qbuf, vtbuf, O_part, l_part);
    hipLaunchKernelGGL(combine_kernel, dim3(256), dim3(256), 0, stream,
                       O_part, l_part, (const unsigned int*)x, d_out);
}